// Round 20
// baseline (175.353 us; speedup 1.0000x reference)
//
#include <hip/hip_runtime.h>
#include <hip/hip_bf16.h>

// CausalSelfAttention on MI355X (gfx950)
// x[4,2048,1024] f32, Wq/Wk/Wv/Wo [1024,1024] f32 -> out [4,2048,1024] f32
// Pipeline: cast->bf16, 8-phase GEMMs (256x128 tile), flash attention.

typedef __bf16 bf16_t;
typedef __bf16 bf16x4 __attribute__((ext_vector_type(4)));
typedef __bf16 bf16x8 __attribute__((ext_vector_type(8)));
typedef float  f32x4  __attribute__((ext_vector_type(4)));

#define MFMA16(a, b, c) __builtin_amdgcn_mfma_f32_16x16x32_bf16(a, b, c, 0, 0, 0)

__device__ __forceinline__ float exp2_(float x) {
#if __has_builtin(__builtin_amdgcn_exp2f)
    return __builtin_amdgcn_exp2f(x);
#else
    return __expf(x * 0.6931471805599453f);
#endif
}

__device__ __forceinline__ void gload_lds16(const bf16_t* g, bf16_t* l) {
    __builtin_amdgcn_global_load_lds(
        (const __attribute__((address_space(1))) void*)g,
        (__attribute__((address_space(3))) void*)l, 16, 0, 0);
}

// ---------------------------------------------------------------- cast (merged)
__global__ __launch_bounds__(256)
void cast_all(const float* __restrict__ x,  const float* __restrict__ Wq,
              const float* __restrict__ Wk, const float* __restrict__ Wv,
              const float* __restrict__ Wo,
              bf16_t* __restrict__ xb, bf16_t* __restrict__ wqkv,
              bf16_t* __restrict__ wob) {
    int i = blockIdx.x * 256 + threadIdx.x;
    const float* src;
    bf16_t* dst;
    if (blockIdx.y == 0) {
        src = x; dst = xb;
    } else {
        if (i >= 524288) return;
        int wsel = i >> 17;                 // 0..3
        int loc  = i & 131071;
        src = wsel == 0 ? Wq : wsel == 1 ? Wk : wsel == 2 ? Wv : Wo;
        dst = wsel == 3 ? wob : wqkv + (size_t)wsel * 1048576;
        i = loc;
    }
    const float4* p = (const float4*)src;
    float4 a = p[i * 2], b = p[i * 2 + 1];
    bf16x8 o;
    o[0] = (bf16_t)a.x; o[1] = (bf16_t)a.y; o[2] = (bf16_t)a.z; o[3] = (bf16_t)a.w;
    o[4] = (bf16_t)b.x; o[5] = (bf16_t)b.y; o[6] = (bf16_t)b.z; o[7] = (bf16_t)b.w;
    *(bf16x8*)(dst + (size_t)i * 8) = o;
}

// ---------------------------------------------------------------- GEMM 256x128 8-phase
template<int OUT_BF16>
__global__ __launch_bounds__(512, 2)
void gemm_8ph(const bf16_t* __restrict__ A, const bf16_t* __restrict__ B,
              void* __restrict__ Cv, int M, int N, int K) {
    __shared__ bf16_t sm[2][24576];   // [buf][ A:256x64 | B:128x64 ], 96 KiB
    const int tid = threadIdx.x;
    const int lane = tid & 63, w = tid >> 6;
    const int wr = w >> 1, wc = w & 1;
    const int g = lane >> 4, c = lane & 15;
    const long bm = (long)blockIdx.x * 256;
    const long bn = (long)blockIdx.y * 128;

    const int srow8 = tid >> 3;             // 0..63
    const int pb = tid & 7;                 // physical 16B slot in row

    auto STAGE_A = [&](int buf, int h, int kt) {
        #pragma unroll
        for (int r = 0; r < 2; ++r) {
            int row = h * 128 + r * 64 + srow8;
            int lb  = pb ^ (row & 7);
            gload_lds16(A + (bm + row) * (long)K + kt * 64 + lb * 8,
                        &sm[buf][row * 64 + pb * 8]);
        }
    };
    auto STAGE_B = [&](int buf, int kt) {
        #pragma unroll
        for (int r = 0; r < 2; ++r) {
            int row = r * 64 + srow8;
            int lb  = pb ^ (row & 7);
            gload_lds16(B + (bn + row) * (long)K + kt * 64 + lb * 8,
                        &sm[buf][16384 + row * 64 + pb * 8]);
        }
    };
    auto LDA = [&](int buf, int m, int k) -> bf16x8 {
        int row = wr * 64 + m * 16 + c;
        return *(const bf16x8*)&sm[buf][row * 64 + (((k * 4 + g) ^ (row & 7)) * 8)];
    };
    auto LDB = [&](int buf, int n, int k) -> bf16x8 {
        int row = wc * 64 + n * 16 + c;
        return *(const bf16x8*)&sm[buf][16384 + row * 64 +
                                        (((k * 4 + g) ^ (row & 7)) * 8)];
    };

#define PHASE(BUF, MM, ISSUE_STMT, WAIT_STMT)                          \
    {                                                                  \
        bf16x8 a0 = LDA(BUF, MM, 0), a1 = LDA(BUF, MM, 1);             \
        ISSUE_STMT;                                                    \
        WAIT_STMT;                                                     \
        __builtin_amdgcn_s_barrier();                                  \
        asm volatile("s_waitcnt lgkmcnt(0)" ::: "memory");             \
        __builtin_amdgcn_sched_barrier(0);                             \
        __builtin_amdgcn_s_setprio(1);                                 \
        _Pragma("unroll")                                              \
        for (int n = 0; n < 4; ++n) {                                  \
            acc[MM][n] = MFMA16(a0, bfr[n][0], acc[MM][n]);            \
            acc[MM][n] = MFMA16(a1, bfr[n][1], acc[MM][n]);            \
        }                                                              \
        __builtin_amdgcn_s_setprio(0);                                 \
        __builtin_amdgcn_s_barrier();                                  \
    }

    f32x4 acc[4][4] = {};
    bf16x8 bfr[4][2];
    const int NJ = K / 128;                 // 2 K-tiles (BK=64) per iteration

    STAGE_B(0, 0); STAGE_A(0, 0, 0); STAGE_A(0, 1, 0);
    STAGE_B(1, 1);
    asm volatile("s_waitcnt vmcnt(2)" ::: "memory");
    __builtin_amdgcn_s_barrier();

    for (int j = 0; j < NJ; ++j) {
        const int t0 = 2 * j;
        const bool more = (j + 1 < NJ);

        #pragma unroll
        for (int n = 0; n < 4; ++n) { bfr[n][0] = LDB(0, n, 0); bfr[n][1] = LDB(0, n, 1); }
        PHASE(0, 0, STAGE_A(1, 0, t0 + 1), (void)0);
        PHASE(0, 1, STAGE_A(1, 1, t0 + 1), (void)0);
        PHASE(0, 2, if (more) STAGE_B(0, t0 + 2), (void)0);
        PHASE(0, 3, (void)0,
              if (more) { asm volatile("s_waitcnt vmcnt(2)" ::: "memory"); }
              else      { asm volatile("s_waitcnt vmcnt(0)" ::: "memory"); });

        #pragma unroll
        for (int n = 0; n < 4; ++n) { bfr[n][0] = LDB(1, n, 0); bfr[n][1] = LDB(1, n, 1); }
        PHASE(1, 0, if (more) STAGE_A(0, 0, t0 + 2), (void)0);
        PHASE(1, 1, if (more) STAGE_A(0, 1, t0 + 2), (void)0);
        PHASE(1, 2, if (more) STAGE_B(1, t0 + 3), (void)0);
        PHASE(1, 3, (void)0,
              if (more) { asm volatile("s_waitcnt vmcnt(2)" ::: "memory"); });
    }
#undef PHASE

    #pragma unroll
    for (int m = 0; m < 4; ++m)
        #pragma unroll
        for (int n = 0; n < 4; ++n)
            #pragma unroll
            for (int i = 0; i < 4; ++i) {
                long row = bm + wr * 64 + m * 16 + g * 4 + i;
                long col = bn + wc * 64 + n * 16 + c;
                float v = acc[m][n][i];
                if (OUT_BF16) ((bf16_t*)Cv)[row * N + col] = (bf16_t)v;
                else          ((float*)Cv)[row * N + col]  = v;
            }
}

// ---------------------------------------------------------------- flash attention
// grid: (64=B*H, 8), block 1024 (16 waves x 16 q-rows = 256 q-rows/block).
// Per-wave state identical to the proven 512-thr version (VGPR ~40, no spill
// risk); K/V staged ONCE per 256 q-rows (waves 0-7 only) -> staging + HBM
// fetch per q-row halves. LDS 70KB -> 2 blocks/CU = 32 waves/CU. 512 blocks
// on 512 slots = single round, q0 = 7-by (big first).

__device__ __forceinline__ void stage_K(const bf16_t* Kp, long rowb, int kb, int hcol,
                                        bf16_t* Kbuf, int tid) {
    int row = tid >> 3;
    int lb  = (tid & 7) ^ (row & 7);
    gload_lds16(Kp + (rowb + kb + row) * 3072 + hcol + lb * 8, Kbuf + tid * 8);
}

__device__ __forceinline__ bf16x8 load_V8(const bf16_t* Vp, long rowb, int kb,
                                          int hcol, int tid) {
    const int d  = tid & 63;
    const int k0 = (tid >> 6) * 8;
    bf16x8 v;
    #pragma unroll
    for (int j = 0; j < 8; ++j)
        v[j] = Vp[(rowb + kb + k0 + j) * 3072 + hcol + d];
    return v;
}

__device__ __forceinline__ void write_V8(bf16_t* Vbuf, int tid, bf16x8 v) {
    const int d  = tid & 63;
    const int k0 = (tid >> 6) * 8;
    *(bf16x8*)&Vbuf[d * 72 + k0] = v;
}

__global__ __launch_bounds__(1024, 8)
void attn_kernel(const bf16_t* __restrict__ Qp, const bf16_t* __restrict__ Kp,
                 const bf16_t* __restrict__ Vp, bf16_t* __restrict__ O) {
    __shared__ bf16_t Ks[2][64 * 64];    // K[key][d], d-blocks XOR-swizzled by key&7
    __shared__ bf16_t Vts[2][64 * 72];   // V^T[d][key], stride 72
    __shared__ bf16_t PW[16][16 * 72];   // per-wave P[q][key], stride 72

    const int tid = threadIdx.x, lane = tid & 63, w = tid >> 6;
    const int g = lane >> 4, c = lane & 15;
    const int bh = blockIdx.x;
    const int b = bh >> 4, h = bh & 15;
    const long rowb = (long)b * 2048;
    const int hcol = h * 64;
    const float QSCL = 0.18033688011112042f;      // 0.125 * log2(e)
    const bool stg = (tid < 512);                 // waves 0-7 do all staging

    const int q0  = 7 - blockIdx.y;               // biggest blocks first
    const int qlo = q0 * 256 + w * 16;            // this wave's 16 q-rows
    const int nkt = 4 * q0 + 4;

    bf16x8 qf[2];
    #pragma unroll
    for (int ks = 0; ks < 2; ++ks) {
        qf[ks] = *(const bf16x8*)(Qp + (rowb + qlo + c) * 3072 +
                                  hcol + ks * 32 + g * 8);
        #pragma unroll
        for (int j = 0; j < 8; ++j)
            qf[ks][j] = (bf16_t)((float)qf[ks][j] * QSCL);
    }

    float m_r = -1e30f;
    float l_r = 0.f;
    f32x4 acc[4] = {};

    if (stg) {
        stage_K(Kp, rowb, 0, hcol, Ks[0], tid);
        write_V8(Vts[0], tid, load_V8(Vp, rowb, 0, hcol, tid));
    }
    __syncthreads();

    for (int t = 0; t < nkt; ++t) {
        const int cur = t & 1;
        const int kb = t * 64;
        const bool pre = (t + 1 < nkt);
        bf16x8 vreg;
        if (pre && stg) {
            stage_K(Kp, rowb, kb + 64, hcol, Ks[cur ^ 1], tid);
            vreg = load_V8(Vp, rowb, kb + 64, hcol, tid);
        }

        if (kb <= qlo + 15) {
            f32x4 sacc[4] = {};
            __builtin_amdgcn_s_setprio(1);
            #pragma unroll
            for (int nt = 0; nt < 4; ++nt) {
                const int row = nt * 16 + c;
                #pragma unroll
                for (int ks = 0; ks < 2; ++ks) {
                    bf16x8 kf = *(const bf16x8*)&Ks[cur][row * 64 +
                                    (((ks * 4 + g) ^ (c & 7)) * 8)];
                    sacc[nt] = MFMA16(kf, qf[ks], sacc[nt]);
                }
            }
            __builtin_amdgcn_s_setprio(0);
            if (kb + 63 > qlo) {
                const int q = qlo + c;
                #pragma unroll
                for (int nt = 0; nt < 4; ++nt)
                    #pragma unroll
                    for (int i = 0; i < 4; ++i) {
                        int key = kb + nt * 16 + g * 4 + i;
                        if (key > q) sacc[nt][i] = -1e30f;
                    }
            }

            float m0 = fmaxf(fmaxf(sacc[0][0], sacc[0][1]),
                             fmaxf(fmaxf(sacc[0][2], sacc[0][3]), sacc[1][0]));
            float m1 = fmaxf(fmaxf(sacc[1][1], sacc[1][2]),
                             fmaxf(fmaxf(sacc[1][3], sacc[2][0]), sacc[2][1]));
            float m2 = fmaxf(fmaxf(sacc[2][2], sacc[2][3]),
                             fmaxf(fmaxf(sacc[3][0], sacc[3][1]),
                                   fmaxf(sacc[3][2], sacc[3][3])));
            float mx = fmaxf(fmaxf(m0, m1), m2);
            if (__any(mx > m_r + 8.f)) {
                mx = fmaxf(mx, __shfl_xor(mx, 16, 64));
                mx = fmaxf(mx, __shfl_xor(mx, 32, 64));
                float mnew = fmaxf(m_r, mx);
                float scl = exp2_(m_r - mnew);
                #pragma unroll
                for (int nt = 0; nt < 4; ++nt)
                    acc[nt] *= scl;
                l_r *= scl;
                m_r = mnew;
            }
            float rsn[4];
            #pragma unroll
            for (int nt = 0; nt < 4; ++nt) {
                #pragma unroll
                for (int i = 0; i < 4; ++i)
                    sacc[nt][i] = exp2_(sacc[nt][i] - m_r);
                rsn[nt] = (sacc[nt][0] + sacc[nt][1]) + (sacc[nt][2] + sacc[nt][3]);
            }
            l_r += (rsn[0] + rsn[1]) + (rsn[2] + rsn[3]);

            #pragma unroll
            for (int nt = 0; nt < 4; ++nt) {
                bf16x4 t4;
                #pragma unroll
                for (int i = 0; i < 4; ++i) t4[i] = (bf16_t)sacc[nt][i];
                *(bf16x4*)&PW[w][c * 72 + nt * 16 + g * 4] = t4;
            }

            __builtin_amdgcn_s_setprio(1);
            #pragma unroll
            for (int ks = 0; ks < 2; ++ks) {
                bf16x8 pf = *(const bf16x8*)&PW[w][c * 72 + ks * 32 + g * 8];
                #pragma unroll
                for (int nt = 0; nt < 4; ++nt) {
                    bf16x8 vf = *(const bf16x8*)&Vts[cur][(nt * 16 + c) * 72 +
                                                          ks * 32 + g * 8];
                    acc[nt] = MFMA16(vf, pf, acc[nt]);
                }
            }
            __builtin_amdgcn_s_setprio(0);
        }

        if (pre && stg) write_V8(Vts[cur ^ 1], tid, vreg);  // write-late (T14)
        __syncthreads();                                    // single barrier per tile
    }

    l_r += __shfl_xor(l_r, 16, 64);
    l_r += __shfl_xor(l_r, 32, 64);
    {
        float rl = __builtin_amdgcn_rcpf(l_r);
        #pragma unroll
        for (int nt = 0; nt < 4; ++nt) {
            bf16x4 t4;
            #pragma unroll
            for (int i = 0; i < 4; ++i) t4[i] = (bf16_t)(acc[nt][i] * rl);
            *(bf16x4*)&PW[w][c * 72 + nt * 16 + g * 4] = t4;
        }
    }
    #pragma unroll
    for (int p = 0; p < 2; ++p) {
        int row = p * 8 + (lane >> 3);
        int ch  = (lane & 7) * 8;
        bf16x8 v = *(const bf16x8*)&PW[w][row * 72 + ch];
        *(bf16x8*)&O[(rowb + qlo + row) * 1024 + hcol + ch] = v;
    }
}

// ---------------------------------------------------------------- launch
extern "C" void kernel_launch(void* const* d_in, const int* in_sizes, int n_in,
                              void* d_out, int out_size, void* d_ws, size_t ws_size,
                              hipStream_t stream) {
    const float* x  = (const float*)d_in[0];
    const float* Wq = (const float*)d_in[1];
    const float* Wk = (const float*)d_in[2];
    const float* Wv = (const float*)d_in[3];
    const float* Wo = (const float*)d_in[4];

    const int M = 8192;
    const int C = 1024;

    char* ws = (char*)d_ws;
    bf16_t* xb   = (bf16_t*)(ws);                          // 16 MB
    bf16_t* wqkv = (bf16_t*)(ws + ((size_t)16 << 20));     //  6 MB ([3072][1024])
    bf16_t* wob  = (bf16_t*)(ws + ((size_t)22 << 20));     //  2 MB
    bf16_t* qkv  = (bf16_t*)(ws + ((size_t)24 << 20));     // 48 MB ([8192][3072])
    bf16_t* aob  = (bf16_t*)(ws + ((size_t)72 << 20));     // 16 MB ([8192][1024])

    cast_all<<<dim3(4096, 2), 256, 0, stream>>>(x, Wq, Wk, Wv, Wo, xb, wqkv, wob);

    // QKV: 256x128 8-phase, grid 768 = 3 even rounds/CU
    gemm_8ph<1><<<dim3(M / 256, 3072 / 128), 512, 0, stream>>>(xb, wqkv, qkv, M, 3072, C);

    // attention: 1024-thr blocks, 256 q-rows each, single round on 512 slots
    attn_kernel<<<dim3(64, 8), 1024, 0, stream>>>(
        qkv, qkv + 1024, qkv + 2048, aob);

    // out-proj: same kernel, grid 256 = exactly 1/CU, fp32 out
    gemm_8ph<0><<<dim3(M / 256, C / 128), 512, 0, stream>>>(aob, wob, d_out, M, C, C);
}

// Round 21
// 159.353 us; speedup vs baseline: 1.1004x; 1.1004x over previous
//
#include <hip/hip_runtime.h>
#include <hip/hip_bf16.h>

// CausalSelfAttention on MI355X (gfx950)
// x[4,2048,1024] f32, Wq/Wk/Wv/Wo [1024,1024] f32 -> out [4,2048,1024] f32
// Pipeline: cast->bf16, 8-phase GEMMs (256x128 tile), flash attention.

typedef __bf16 bf16_t;
typedef __bf16 bf16x4 __attribute__((ext_vector_type(4)));
typedef __bf16 bf16x8 __attribute__((ext_vector_type(8)));
typedef float  f32x4  __attribute__((ext_vector_type(4)));

#define MFMA16(a, b, c) __builtin_amdgcn_mfma_f32_16x16x32_bf16(a, b, c, 0, 0, 0)

__device__ __forceinline__ float exp2_(float x) {
#if __has_builtin(__builtin_amdgcn_exp2f)
    return __builtin_amdgcn_exp2f(x);
#else
    return __expf(x * 0.6931471805599453f);
#endif
}

__device__ __forceinline__ void gload_lds16(const bf16_t* g, bf16_t* l) {
    __builtin_amdgcn_global_load_lds(
        (const __attribute__((address_space(1))) void*)g,
        (__attribute__((address_space(3))) void*)l, 16, 0, 0);
}

// ---------------------------------------------------------------- cast (merged)
__global__ __launch_bounds__(256)
void cast_all(const float* __restrict__ x,  const float* __restrict__ Wq,
              const float* __restrict__ Wk, const float* __restrict__ Wv,
              const float* __restrict__ Wo,
              bf16_t* __restrict__ xb, bf16_t* __restrict__ wqkv,
              bf16_t* __restrict__ wob) {
    int i = blockIdx.x * 256 + threadIdx.x;
    const float* src;
    bf16_t* dst;
    if (blockIdx.y == 0) {
        src = x; dst = xb;
    } else {
        if (i >= 524288) return;
        int wsel = i >> 17;                 // 0..3
        int loc  = i & 131071;
        src = wsel == 0 ? Wq : wsel == 1 ? Wk : wsel == 2 ? Wv : Wo;
        dst = wsel == 3 ? wob : wqkv + (size_t)wsel * 1048576;
        i = loc;
    }
    const float4* p = (const float4*)src;
    float4 a = p[i * 2], b = p[i * 2 + 1];
    bf16x8 o;
    o[0] = (bf16_t)a.x; o[1] = (bf16_t)a.y; o[2] = (bf16_t)a.z; o[3] = (bf16_t)a.w;
    o[4] = (bf16_t)b.x; o[5] = (bf16_t)b.y; o[6] = (bf16_t)b.z; o[7] = (bf16_t)b.w;
    *(bf16x8*)(dst + (size_t)i * 8) = o;
}

// ---------------------------------------------------------------- GEMM 256x128 8-phase
// T3+T4+T5. 512 thr / 8 waves (wr=w>>1 rows, wc=w&1 cols), per-wave C = 64x64.
// BK=64, 2 K-tiles/iter, 8 phases (1 m-frag, 8 MFMA each). Counted vmcnt(2) at
// ph3/ph7 only. Per-row 16B-block XOR swizzle, pre-swizzled global source.
template<int OUT_BF16>
__global__ __launch_bounds__(512, 2)
void gemm_8ph(const bf16_t* __restrict__ A, const bf16_t* __restrict__ B,
              void* __restrict__ Cv, int M, int N, int K) {
    __shared__ bf16_t sm[2][24576];   // [buf][ A:256x64 | B:128x64 ], 96 KiB
    const int tid = threadIdx.x;
    const int lane = tid & 63, w = tid >> 6;
    const int wr = w >> 1, wc = w & 1;
    const int g = lane >> 4, c = lane & 15;
    const long bm = (long)blockIdx.x * 256;
    const long bn = (long)blockIdx.y * 128;

    const int srow8 = tid >> 3;             // 0..63
    const int pb = tid & 7;                 // physical 16B slot in row

    auto STAGE_A = [&](int buf, int h, int kt) {
        #pragma unroll
        for (int r = 0; r < 2; ++r) {
            int row = h * 128 + r * 64 + srow8;
            int lb  = pb ^ (row & 7);
            gload_lds16(A + (bm + row) * (long)K + kt * 64 + lb * 8,
                        &sm[buf][row * 64 + pb * 8]);
        }
    };
    auto STAGE_B = [&](int buf, int kt) {
        #pragma unroll
        for (int r = 0; r < 2; ++r) {
            int row = r * 64 + srow8;
            int lb  = pb ^ (row & 7);
            gload_lds16(B + (bn + row) * (long)K + kt * 64 + lb * 8,
                        &sm[buf][16384 + row * 64 + pb * 8]);
        }
    };
    auto LDA = [&](int buf, int m, int k) -> bf16x8 {
        int row = wr * 64 + m * 16 + c;
        return *(const bf16x8*)&sm[buf][row * 64 + (((k * 4 + g) ^ (row & 7)) * 8)];
    };
    auto LDB = [&](int buf, int n, int k) -> bf16x8 {
        int row = wc * 64 + n * 16 + c;
        return *(const bf16x8*)&sm[buf][16384 + row * 64 +
                                        (((k * 4 + g) ^ (row & 7)) * 8)];
    };

#define PHASE(BUF, MM, ISSUE_STMT, WAIT_STMT)                          \
    {                                                                  \
        bf16x8 a0 = LDA(BUF, MM, 0), a1 = LDA(BUF, MM, 1);             \
        ISSUE_STMT;                                                    \
        WAIT_STMT;                                                     \
        __builtin_amdgcn_s_barrier();                                  \
        asm volatile("s_waitcnt lgkmcnt(0)" ::: "memory");             \
        __builtin_amdgcn_sched_barrier(0);                             \
        __builtin_amdgcn_s_setprio(1);                                 \
        _Pragma("unroll")                                              \
        for (int n = 0; n < 4; ++n) {                                  \
            acc[MM][n] = MFMA16(a0, bfr[n][0], acc[MM][n]);            \
            acc[MM][n] = MFMA16(a1, bfr[n][1], acc[MM][n]);            \
        }                                                              \
        __builtin_amdgcn_s_setprio(0);                                 \
        __builtin_amdgcn_s_barrier();                                  \
    }

    f32x4 acc[4][4] = {};
    bf16x8 bfr[4][2];
    const int NJ = K / 128;                 // 2 K-tiles (BK=64) per iteration

    // prologue: t0 full (B,A0,A1), t1.B; vmcnt(2) leaves t1.B in flight
    STAGE_B(0, 0); STAGE_A(0, 0, 0); STAGE_A(0, 1, 0);
    STAGE_B(1, 1);
    asm volatile("s_waitcnt vmcnt(2)" ::: "memory");
    __builtin_amdgcn_s_barrier();

    for (int j = 0; j < NJ; ++j) {
        const int t0 = 2 * j;
        const bool more = (j + 1 < NJ);

        // ---- tile t0 (buf0): phases 0..3
        #pragma unroll
        for (int n = 0; n < 4; ++n) { bfr[n][0] = LDB(0, n, 0); bfr[n][1] = LDB(0, n, 1); }
        PHASE(0, 0, STAGE_A(1, 0, t0 + 1), (void)0);
        PHASE(0, 1, STAGE_A(1, 1, t0 + 1), (void)0);
        PHASE(0, 2, if (more) STAGE_B(0, t0 + 2), (void)0);
        PHASE(0, 3, (void)0,
              if (more) { asm volatile("s_waitcnt vmcnt(2)" ::: "memory"); }
              else      { asm volatile("s_waitcnt vmcnt(0)" ::: "memory"); });

        // ---- tile t0+1 (buf1): phases 4..7
        #pragma unroll
        for (int n = 0; n < 4; ++n) { bfr[n][0] = LDB(1, n, 0); bfr[n][1] = LDB(1, n, 1); }
        PHASE(1, 0, if (more) STAGE_A(0, 0, t0 + 2), (void)0);
        PHASE(1, 1, if (more) STAGE_A(0, 1, t0 + 2), (void)0);
        PHASE(1, 2, if (more) STAGE_B(1, t0 + 3), (void)0);
        PHASE(1, 3, (void)0,
              if (more) { asm volatile("s_waitcnt vmcnt(2)" ::: "memory"); });
    }
#undef PHASE

    #pragma unroll
    for (int m = 0; m < 4; ++m)
        #pragma unroll
        for (int n = 0; n < 4; ++n)
            #pragma unroll
            for (int i = 0; i < 4; ++i) {
                long row = bm + wr * 64 + m * 16 + g * 4 + i;
                long col = bn + wc * 64 + n * 16 + c;
                float v = acc[m][n][i];
                if (OUT_BF16) ((bf16_t*)Cv)[row * N + col] = (bf16_t)v;
                else          ((float*)Cv)[row * N + col]  = v;
            }
}

// ---------------------------------------------------------------- flash attention
// grid: (64=B*H, 16), block 512 (8 waves x 16 q-rows). q0 = by<8 ? 15-by : by-8.
// Swapped QK^T (lane owns one q-row), defer-max with PER-LANE partial max/sum,
// conflict-free V-transpose staging, setprio. This exact envelope (512 thr,
// 6 waves/EU, VGPR 40) is the only one that doesn't spill: R10/R14/R17/R20
// all hit register cliffs with larger per-wave or per-block state.

__device__ __forceinline__ void stage_K(const bf16_t* Kp, long rowb, int kb, int hcol,
                                        bf16_t* Kbuf, int tid) {
    int row = tid >> 3;
    int lb  = (tid & 7) ^ (row & 7);
    gload_lds16(Kp + (rowb + kb + row) * 3072 + hcol + lb * 8, Kbuf + tid * 8);
}

__device__ __forceinline__ bf16x8 load_V8(const bf16_t* Vp, long rowb, int kb,
                                          int hcol, int tid) {
    const int d  = tid & 63;
    const int k0 = (tid >> 6) * 8;
    bf16x8 v;
    #pragma unroll
    for (int j = 0; j < 8; ++j)
        v[j] = Vp[(rowb + kb + k0 + j) * 3072 + hcol + d];
    return v;
}

__device__ __forceinline__ void write_V8(bf16_t* Vbuf, int tid, bf16x8 v) {
    const int d  = tid & 63;
    const int k0 = (tid >> 6) * 8;
    *(bf16x8*)&Vbuf[d * 72 + k0] = v;
}

__global__ __launch_bounds__(512, 6)
void attn_kernel(const bf16_t* __restrict__ Qp, const bf16_t* __restrict__ Kp,
                 const bf16_t* __restrict__ Vp, bf16_t* __restrict__ O) {
    __shared__ bf16_t Ks[2][64 * 64];    // K[key][d], d-blocks XOR-swizzled by key&7
    __shared__ bf16_t Vts[2][64 * 72];   // V^T[d][key], stride 72
    __shared__ bf16_t PW[8][16 * 72];    // per-wave P[q][key], stride 72

    const int tid = threadIdx.x, lane = tid & 63, w = tid >> 6;
    const int g = lane >> 4, c = lane & 15;
    const int bh = blockIdx.x;
    const int b = bh >> 4, h = bh & 15;
    const long rowb = (long)b * 2048;
    const int hcol = h * 64;
    const float QSCL = 0.18033688011112042f;      // 0.125 * log2(e)

    const int by = blockIdx.y;
    const int q0 = by < 8 ? 15 - by : by - 8;     // desc round 1, asc round 2
    const int qlo = q0 * 128 + w * 16;
    const int nkt = 2 * q0 + 2;

    bf16x8 qf[2];
    #pragma unroll
    for (int ks = 0; ks < 2; ++ks) {
        qf[ks] = *(const bf16x8*)(Qp + (rowb + qlo + c) * 3072 +
                                  hcol + ks * 32 + g * 8);
        #pragma unroll
        for (int j = 0; j < 8; ++j)
            qf[ks][j] = (bf16_t)((float)qf[ks][j] * QSCL);
    }

    float m_r = -1e30f;
    float l_r = 0.f;
    f32x4 acc[4] = {};

    stage_K(Kp, rowb, 0, hcol, Ks[0], tid);
    write_V8(Vts[0], tid, load_V8(Vp, rowb, 0, hcol, tid));
    __syncthreads();

    for (int t = 0; t < nkt; ++t) {
        const int cur = t & 1;
        const int kb = t * 64;
        const bool pre = (t + 1 < nkt);
        bf16x8 vreg;
        if (pre) {
            stage_K(Kp, rowb, kb + 64, hcol, Ks[cur ^ 1], tid);
            vreg = load_V8(Vp, rowb, kb + 64, hcol, tid);
        }

        if (kb <= qlo + 15) {
            f32x4 sacc[4] = {};
            __builtin_amdgcn_s_setprio(1);
            #pragma unroll
            for (int nt = 0; nt < 4; ++nt) {
                const int row = nt * 16 + c;
                #pragma unroll
                for (int ks = 0; ks < 2; ++ks) {
                    bf16x8 kf = *(const bf16x8*)&Ks[cur][row * 64 +
                                    (((ks * 4 + g) ^ (c & 7)) * 8)];
                    sacc[nt] = MFMA16(kf, qf[ks], sacc[nt]);
                }
            }
            __builtin_amdgcn_s_setprio(0);
            if (kb + 63 > qlo) {
                const int q = qlo + c;
                #pragma unroll
                for (int nt = 0; nt < 4; ++nt)
                    #pragma unroll
                    for (int i = 0; i < 4; ++i) {
                        int key = kb + nt * 16 + g * 4 + i;
                        if (key > q) sacc[nt][i] = -1e30f;
                    }
            }

            float m0 = fmaxf(fmaxf(sacc[0][0], sacc[0][1]),
                             fmaxf(fmaxf(sacc[0][2], sacc[0][3]), sacc[1][0]));
            float m1 = fmaxf(fmaxf(sacc[1][1], sacc[1][2]),
                             fmaxf(fmaxf(sacc[1][3], sacc[2][0]), sacc[2][1]));
            float m2 = fmaxf(fmaxf(sacc[2][2], sacc[2][3]),
                             fmaxf(fmaxf(sacc[3][0], sacc[3][1]),
                                   fmaxf(sacc[3][2], sacc[3][3])));
            float mx = fmaxf(fmaxf(m0, m1), m2);
            if (__any(mx > m_r + 8.f)) {
                mx = fmaxf(mx, __shfl_xor(mx, 16, 64));
                mx = fmaxf(mx, __shfl_xor(mx, 32, 64));
                float mnew = fmaxf(m_r, mx);
                float scl = exp2_(m_r - mnew);
                #pragma unroll
                for (int nt = 0; nt < 4; ++nt)
                    acc[nt] *= scl;
                l_r *= scl;
                m_r = mnew;
            }
            float rsn[4];
            #pragma unroll
            for (int nt = 0; nt < 4; ++nt) {
                #pragma unroll
                for (int i = 0; i < 4; ++i)
                    sacc[nt][i] = exp2_(sacc[nt][i] - m_r);
                rsn[nt] = (sacc[nt][0] + sacc[nt][1]) + (sacc[nt][2] + sacc[nt][3]);
            }
            l_r += (rsn[0] + rsn[1]) + (rsn[2] + rsn[3]);

            #pragma unroll
            for (int nt = 0; nt < 4; ++nt) {
                bf16x4 t4;
                #pragma unroll
                for (int i = 0; i < 4; ++i) t4[i] = (bf16_t)sacc[nt][i];
                *(bf16x4*)&PW[w][c * 72 + nt * 16 + g * 4] = t4;
            }

            __builtin_amdgcn_s_setprio(1);
            #pragma unroll
            for (int ks = 0; ks < 2; ++ks) {
                bf16x8 pf = *(const bf16x8*)&PW[w][c * 72 + ks * 32 + g * 8];
                #pragma unroll
                for (int nt = 0; nt < 4; ++nt) {
                    bf16x8 vf = *(const bf16x8*)&Vts[cur][(nt * 16 + c) * 72 +
                                                          ks * 32 + g * 8];
                    acc[nt] = MFMA16(vf, pf, acc[nt]);
                }
            }
            __builtin_amdgcn_s_setprio(0);
        }

        if (pre) write_V8(Vts[cur ^ 1], tid, vreg);  // write-late (T14)
        __syncthreads();                             // single barrier per tile
    }

    l_r += __shfl_xor(l_r, 16, 64);
    l_r += __shfl_xor(l_r, 32, 64);
    {
        float rl = __builtin_amdgcn_rcpf(l_r);
        #pragma unroll
        for (int nt = 0; nt < 4; ++nt) {
            bf16x4 t4;
            #pragma unroll
            for (int i = 0; i < 4; ++i) t4[i] = (bf16_t)(acc[nt][i] * rl);
            *(bf16x4*)&PW[w][c * 72 + nt * 16 + g * 4] = t4;
        }
    }
    #pragma unroll
    for (int p = 0; p < 2; ++p) {
        int row = p * 8 + (lane >> 3);
        int ch  = (lane & 7) * 8;
        bf16x8 v = *(const bf16x8*)&PW[w][row * 72 + ch];
        *(bf16x8*)&O[(rowb + qlo + row) * 1024 + hcol + ch] = v;
    }
}

// ---------------------------------------------------------------- launch
extern "C" void kernel_launch(void* const* d_in, const int* in_sizes, int n_in,
                              void* d_out, int out_size, void* d_ws, size_t ws_size,
                              hipStream_t stream) {
    const float* x  = (const float*)d_in[0];
    const float* Wq = (const float*)d_in[1];
    const float* Wk = (const float*)d_in[2];
    const float* Wv = (const float*)d_in[3];
    const float* Wo = (const float*)d_in[4];

    const int M = 8192;
    const int C = 1024;

    char* ws = (char*)d_ws;
    bf16_t* xb   = (bf16_t*)(ws);                          // 16 MB
    bf16_t* wqkv = (bf16_t*)(ws + ((size_t)16 << 20));     //  6 MB ([3072][1024])
    bf16_t* wob  = (bf16_t*)(ws + ((size_t)22 << 20));     //  2 MB
    bf16_t* qkv  = (bf16_t*)(ws + ((size_t)24 << 20));     // 48 MB ([8192][3072])
    bf16_t* aob  = (bf16_t*)(ws + ((size_t)72 << 20));     // 16 MB ([8192][1024])

    cast_all<<<dim3(4096, 2), 256, 0, stream>>>(x, Wq, Wk, Wv, Wo, xb, wqkv, wob);

    // QKV: 256x128 8-phase, grid 768 = 3 even rounds/CU
    gemm_8ph<1><<<dim3(M / 256, 3072 / 128), 512, 0, stream>>>(xb, wqkv, qkv, M, 3072, C);

    attn_kernel<<<dim3(64, 16), 512, 0, stream>>>(
        qkv, qkv + 1024, qkv + 2048, aob);

    // out-proj: same kernel, grid 256 = exactly 1/CU, fp32 out
    gemm_8ph<0><<<dim3(M / 256, C / 128), 512, 0, stream>>>(aob, wob, d_out, M, C, C);
}